// Round 4
// baseline (396.277 us; speedup 1.0000x reference)
//
#include <hip/hip_runtime.h>
#include <hip/hip_bf16.h>
#include <hip/hip_fp16.h>
#include <math.h>

#define NEG_SLOPE 0.2f

typedef __attribute__((ext_vector_type(8))) short short8v;
typedef __attribute__((ext_vector_type(4))) float f32x4;

__device__ __forceinline__ float uas(unsigned int u) { return __uint_as_float(u); }

__device__ __forceinline__ unsigned short f2bf(float x) {
    __hip_bfloat16 b = __float2bfloat16(x);
    return *(unsigned short*)&b;
}

// pick head's fp16 exp value from packed uint2 (head = 0..3)
__device__ __forceinline__ float pick_ex(uint2 e, int head) {
    unsigned int p  = (head & 2) ? e.y : e.x;
    unsigned short us = (unsigned short)((head & 1) ? (p >> 16) : (p & 0xFFFFu));
    __half hv;
    *(unsigned short*)&hv = us;
    return __half2float(hv);
}

// ---------------- W prep: fp32 W[128,256] -> bf16 fragment-ordered wfrag -----
// slot(kstep,ntile) at shorts[(kstep*8+ntile)*512]; lane L holds
// B[n=16*ntile+(L&15)][k=32*kstep+(L>>4)*8+j], j=0..7 -> lane-contiguous 16B.
__global__ void k_prep(const float* __restrict__ W, short* __restrict__ wfrag) {
    int p = blockIdx.x * 256 + threadIdx.x;   // 0..4095
    if (p >= 4096) return;
    int n = p & 127, kg = p >> 7;             // kg: k-group of 8
    const float* wp = W + (size_t)n * 256 + kg * 8;
    float4 v0 = *(const float4*)wp;
    float4 v1 = *(const float4*)(wp + 4);
    short s8[8];
    s8[0] = (short)f2bf(v0.x); s8[1] = (short)f2bf(v0.y);
    s8[2] = (short)f2bf(v0.z); s8[3] = (short)f2bf(v0.w);
    s8[4] = (short)f2bf(v1.x); s8[5] = (short)f2bf(v1.y);
    s8[6] = (short)f2bf(v1.z); s8[7] = (short)f2bf(v1.w);
    int kstep = kg >> 2, ntile = n >> 4;
    int L     = (kg & 3) * 16 + (n & 15);
    int slot  = kstep * 8 + ntile;
    *(short8v*)&wfrag[(slot * 64 + L) * 8] = *(short8v*)s8;
}

// ---------------- MFMA GEMM + fused el/er ------------------------------------
// block = 256 thr (4 waves); tile 128 nodes x 128 outs; 16x16x32 bf16 MFMA.
// No LDS: B-fragments read from global wfrag (64 KB, L2-broadcast).
__global__ __launch_bounds__(256) void k_gemm(const float* __restrict__ feat,
                                              const short* __restrict__ wfrag,
                                              unsigned short* __restrict__ hb,
                                              float* __restrict__ el, float* __restrict__ er,
                                              const float* __restrict__ al,
                                              const float* __restrict__ ar, int N) {
    const int t    = threadIdx.x;
    const int lane = t & 63;
    const int wave = t >> 6;
    const int n0   = blockIdx.x * 128;
    const int wm0  = wave * 32;
    const int g    = lane >> 4;     // k-quad
    const int c    = lane & 15;

    int row0 = n0 + wm0 + c;
    int row1 = row0 + 16;
    int r0c = row0 < N ? row0 : N - 1;
    int r1c = row1 < N ? row1 : N - 1;

    f32x4 acc[2][8];
#pragma unroll
    for (int mt = 0; mt < 2; mt++)
#pragma unroll
        for (int nt = 0; nt < 8; nt++) acc[mt][nt] = (f32x4){0.f, 0.f, 0.f, 0.f};

#pragma unroll
    for (int ks = 0; ks < 8; ks++) {
        short8v afrag[2];
#pragma unroll
        for (int mt = 0; mt < 2; mt++) {
            const float* ap = feat + (size_t)(mt ? r1c : r0c) * 256 + ks * 32 + g * 8;
            float4 v0 = *(const float4*)ap;
            float4 v1 = *(const float4*)(ap + 4);
            short s8[8];
            s8[0] = (short)f2bf(v0.x); s8[1] = (short)f2bf(v0.y);
            s8[2] = (short)f2bf(v0.z); s8[3] = (short)f2bf(v0.w);
            s8[4] = (short)f2bf(v1.x); s8[5] = (short)f2bf(v1.y);
            s8[6] = (short)f2bf(v1.z); s8[7] = (short)f2bf(v1.w);
            afrag[mt] = *(short8v*)s8;
        }
#pragma unroll
        for (int nt = 0; nt < 8; nt++) {
            short8v b = *(const short8v*)&wfrag[((ks * 8 + nt) * 64 + lane) * 8];
            acc[0][nt] = __builtin_amdgcn_mfma_f32_16x16x32_bf16(afrag[0], b, acc[0][nt], 0, 0, 0);
            acc[1][nt] = __builtin_amdgcn_mfma_f32_16x16x32_bf16(afrag[1], b, acc[1][nt], 0, 0, 0);
        }
    }

    // epilogue: C/D layout col = nt*16 + c, row = wm0 + mt*16 + g*4 + r
    float al8[8], ar8[8];
#pragma unroll
    for (int nt = 0; nt < 8; nt++) {
        al8[nt] = al[nt * 16 + c];
        ar8[nt] = ar[nt * 16 + c];
    }
#pragma unroll
    for (int mt = 0; mt < 2; mt++)
#pragma unroll
        for (int r = 0; r < 4; r++) {
            int m = n0 + wm0 + mt * 16 + g * 4 + r;
            float v[8];
#pragma unroll
            for (int nt = 0; nt < 8; nt++) v[nt] = acc[mt][nt][r];
            if (m < N) {
#pragma unroll
                for (int nt = 0; nt < 8; nt++)
                    hb[(size_t)m * 128 + nt * 16 + c] = f2bf(v[nt]);
            }
            // fused el/er: head hh covers cols [32*hh, 32*hh+32) = nt 2hh,2hh+1
            float pl[4], pr[4];
#pragma unroll
            for (int hh = 0; hh < 4; hh++) {
                pl[hh] = v[2 * hh] * al8[2 * hh] + v[2 * hh + 1] * al8[2 * hh + 1];
                pr[hh] = v[2 * hh] * ar8[2 * hh] + v[2 * hh + 1] * ar8[2 * hh + 1];
            }
#pragma unroll
            for (int o = 1; o < 16; o <<= 1) {
#pragma unroll
                for (int hh = 0; hh < 4; hh++) {
                    pl[hh] += __shfl_xor(pl[hh], o);
                    pr[hh] += __shfl_xor(pr[hh], o);
                }
            }
            if (c == 0 && m < N) {
                float4 lv = {pl[0], pl[1], pl[2], pl[3]};
                float4 rv = {pr[0], pr[1], pr[2], pr[3]};
                *(float4*)(el + (size_t)m * 4) = lv;
                *(float4*)(er + (size_t)m * 4) = rv;
            }
        }
}

// ---------------- CSR build: count / assign ----------------------------------
__global__ void k_count(const int* __restrict__ dst, int* __restrict__ deg, int E) {
    int g = blockIdx.x * blockDim.x + threadIdx.x;
    if (g < E) atomicAdd(&deg[dst[g]], 1);
}

__global__ void k_assign(const int* __restrict__ deg, int* __restrict__ start,
                         int* __restrict__ cursor, int* __restrict__ counter, int N) {
    int g = blockIdx.x * blockDim.x + threadIdx.x;
    int lane = threadIdx.x & 63;
    int d = (g < N) ? deg[g] : 0;
    int incl = d;
#pragma unroll
    for (int o = 1; o < 64; o <<= 1) {
        int y = __shfl_up(incl, o);
        if (lane >= o) incl += y;
    }
    int excl  = incl - d;
    int total = __shfl(incl, 63);
    int base  = 0;
    if (lane == 0) base = atomicAdd(counter, total);
    base = __shfl(base, 0);
    if (g < N) { start[g] = base + excl; cursor[g] = base + excl; }
}

// ---------------- scatter + score: CSR payload (src, fp16 exp(leaky)) --------
// No segment-max subtraction: scores are O(few), exp(score) <~ 40 — fp16-safe,
// softmax ratio unchanged.
__global__ void k_scatter(const int* __restrict__ src, const int* __restrict__ dst,
                          const float* __restrict__ el, const float* __restrict__ er,
                          int* __restrict__ cursor, int* __restrict__ src_csr,
                          uint2* __restrict__ ex_csr, int E) {
    int g = blockIdx.x * blockDim.x + threadIdx.x;
    if (g >= E) return;
    int s = src[g], d = dst[g];
    int p = atomicAdd(&cursor[d], 1);
    float4 l = *(const float4*)(el + (size_t)s * 4);
    float4 r = *(const float4*)(er + (size_t)d * 4);
    float t0 = l.x + r.x, t1 = l.y + r.y, t2 = l.z + r.z, t3 = l.w + r.w;
    t0 = t0 > 0.f ? t0 : NEG_SLOPE * t0;
    t1 = t1 > 0.f ? t1 : NEG_SLOPE * t1;
    t2 = t2 > 0.f ? t2 : NEG_SLOPE * t2;
    t3 = t3 > 0.f ? t3 : NEG_SLOPE * t3;
    __half2 lo = __floats2half2_rn(__expf(t0), __expf(t1));
    __half2 hi = __floats2half2_rn(__expf(t2), __expf(t3));
    uint2 pack;
    pack.x = *(unsigned int*)&lo;
    pack.y = *(unsigned int*)&hi;
    src_csr[p] = s;
    ex_csr[p]  = pack;
}

// ---------------- gather-side aggregation: one wave per dst node -------------
// out[n] = bias + hb[n]*sum_e hb[src_e] + (sum_e ex_e hb[src_e]) / sum_e ex_e
__global__ __launch_bounds__(256) void k_agg(
        const unsigned int* __restrict__ hbu,
        const uint2* __restrict__ ex_csr, const int* __restrict__ src_csr,
        const int* __restrict__ start, const int* __restrict__ deg,
        const float* __restrict__ bias, float* __restrict__ out, int N) {
    int wid  = blockIdx.x * 4 + (threadIdx.x >> 6);
    int lane = threadIdx.x & 63;
    if (wid >= N) return;
    int beg = __builtin_amdgcn_readfirstlane(start[wid]);
    int dg  = __builtin_amdgcn_readfirstlane(deg[wid]);
    int head = lane >> 4;   // elements (2*lane, 2*lane+1) share one head

    float S1x = 0.f, S1y = 0.f, S2x = 0.f, S2y = 0.f, dd = 0.f;
    int i = 0;
    for (; i + 4 <= dg; i += 4) {
        int b = beg + i;
        int s0 = src_csr[b], s1 = src_csr[b + 1], s2 = src_csr[b + 2], s3 = src_csr[b + 3];
        uint2 e0 = ex_csr[b], e1 = ex_csr[b + 1], e2 = ex_csr[b + 2], e3 = ex_csr[b + 3];
        unsigned int u0 = hbu[(size_t)s0 * 64 + lane];
        unsigned int u1 = hbu[(size_t)s1 * 64 + lane];
        unsigned int u2 = hbu[(size_t)s2 * 64 + lane];
        unsigned int u3 = hbu[(size_t)s3 * 64 + lane];
        float x0 = uas(u0 << 16), y0 = uas(u0 & 0xFFFF0000u);
        float x1 = uas(u1 << 16), y1 = uas(u1 & 0xFFFF0000u);
        float x2 = uas(u2 << 16), y2 = uas(u2 & 0xFFFF0000u);
        float x3 = uas(u3 << 16), y3 = uas(u3 & 0xFFFF0000u);
        float w0 = pick_ex(e0, head), w1 = pick_ex(e1, head);
        float w2 = pick_ex(e2, head), w3 = pick_ex(e3, head);
        S1x += (x0 + x1) + (x2 + x3);
        S1y += (y0 + y1) + (y2 + y3);
        S2x += w0 * x0 + w1 * x1 + w2 * x2 + w3 * x3;
        S2y += w0 * y0 + w1 * y1 + w2 * y2 + w3 * y3;
        dd  += (w0 + w1) + (w2 + w3);
    }
    for (; i < dg; i++) {
        int b = beg + i;
        int s0 = src_csr[b];
        uint2 e0 = ex_csr[b];
        unsigned int u0 = hbu[(size_t)s0 * 64 + lane];
        float x0 = uas(u0 << 16), y0 = uas(u0 & 0xFFFF0000u);
        float w0 = pick_ex(e0, head);
        S1x += x0; S1y += y0;
        S2x += w0 * x0; S2y += w0 * y0;
        dd  += w0;
    }

    unsigned int uh = hbu[(size_t)wid * 64 + lane];
    float hvx = uas(uh << 16), hvy = uas(uh & 0xFFFF0000u);
    float2 bv = ((const float2*)bias)[lane];
    float inv = dd > 0.f ? 1.f / dd : 0.f;
    float ox = bv.x + hvx * S1x + S2x * inv;
    float oy = bv.y + hvy * S1y + S2y * inv;
    float2 o = {ox, oy};
    ((float2*)(out + (size_t)wid * 128))[lane] = o;
}

extern "C" void kernel_launch(void* const* d_in, const int* in_sizes, int n_in,
                              void* d_out, int out_size, void* d_ws, size_t ws_size,
                              hipStream_t stream) {
    const float* feat = (const float*)d_in[0];
    const float* W_fc = (const float*)d_in[1];
    const float* al   = (const float*)d_in[2];
    const float* ar   = (const float*)d_in[3];
    const float* bias = (const float*)d_in[4];
    const int*   src  = (const int*)d_in[5];
    const int*   dst  = (const int*)d_in[6];
    const int N = in_sizes[0] / 256;
    const int E = in_sizes[5];

    char* ws = (char*)d_ws;
    size_t off = 0;
    unsigned int* hbu = (unsigned int*)(ws + off); off += (size_t)N * 64 * 4; // 25.6 MB
    float* el         = (float*)(ws + off); off += (size_t)N * 4 * 4;         // 1.6 MB
    float* er         = (float*)(ws + off); off += (size_t)N * 4 * 4;         // 1.6 MB
    int* deg          = (int*)(ws + off);   off += (size_t)N * 4;             // \ one
    int* counter      = (int*)(ws + off);   off += 256;                       // / memset
    int* startA       = (int*)(ws + off);   off += (size_t)N * 4;
    int* cursor       = (int*)(ws + off);   off += (size_t)N * 4;
    int* src_csr      = (int*)(ws + off);   off += (size_t)E * 4;             // 4 MB
    uint2* ex_csr     = (uint2*)(ws + off); off += (size_t)E * 8;             // 8 MB
    short* wfrag      = (short*)(ws + off); off += 32768 * 2;                 // 64 KB

    float* out = (float*)d_out;

    hipMemsetAsync(deg, 0, (size_t)N * 4 + 256, stream);   // deg + counter
    k_prep<<<16, 256, 0, stream>>>(W_fc, wfrag);
    k_gemm<<<(N + 127) / 128, 256, 0, stream>>>(feat, wfrag, (unsigned short*)hbu,
                                                el, er, al, ar, N);
    k_count<<<(E + 255) / 256, 256, 0, stream>>>(dst, deg, E);
    k_assign<<<(N + 255) / 256, 256, 0, stream>>>(deg, startA, cursor, counter, N);
    k_scatter<<<(E + 255) / 256, 256, 0, stream>>>(src, dst, el, er, cursor,
                                                   src_csr, ex_csr, E);
    k_agg<<<(N + 3) / 4, 256, 0, stream>>>(hbu, ex_csr, src_csr, startA, deg,
                                           bias, out, N);
}

// Round 5
// 366.598 us; speedup vs baseline: 1.0810x; 1.0810x over previous
//
#include <hip/hip_runtime.h>
#include <hip/hip_bf16.h>
#include <hip/hip_fp16.h>
#include <math.h>

#define NEG_SLOPE 0.2f

typedef __attribute__((ext_vector_type(8))) short short8v;
typedef __attribute__((ext_vector_type(4))) float f32x4;

__device__ __forceinline__ float uas(unsigned int u) { return __uint_as_float(u); }

__device__ __forceinline__ unsigned short f2bf(float x) {
    __hip_bfloat16 b = __float2bfloat16(x);
    return *(unsigned short*)&b;
}

// pick head's fp16 exp value from packed uint2 (head = 0..3)
__device__ __forceinline__ float pick_ex(uint2 e, int head) {
    unsigned int p  = (head & 2) ? e.y : e.x;
    unsigned short us = (unsigned short)((head & 1) ? (p >> 16) : (p & 0xFFFFu));
    __half hv;
    *(unsigned short*)&hv = us;
    return __half2float(hv);
}

// ---------------- W prep: extended bf16 fragment image -----------------------
// Extended B matrix W'[144,256]: rows 0..127 = W; rows 128..135 = head-masked
// attn projections vl[4],vr[4] (vl[hh][k] = sum_{c in head hh} W[c][k]*al[c]),
// rows 136..143 = 0.  Fragment layout (9 ntiles):
//   slot(kstep,ntile) = kstep*9+ntile; lane L=(kg&3)*16+(n&15) holds 8 shorts
//   B'[n][k=kstep*32+(L>>4)*8+j]  -> lane-contiguous 16 B.
__global__ void k_prep(const float* __restrict__ W, const float* __restrict__ al,
                       const float* __restrict__ ar, short* __restrict__ wfrag) {
    int p = blockIdx.x * 256 + threadIdx.x;   // n*32+kg, 0..4607
    if (p >= 144 * 32) return;
    int n = p >> 5, kg = p & 31;
    float v[8];
    if (n < 128) {
        const float* wp = W + (size_t)n * 256 + kg * 8;
        float4 v0 = *(const float4*)wp;
        float4 v1 = *(const float4*)(wp + 4);
        v[0] = v0.x; v[1] = v0.y; v[2] = v0.z; v[3] = v0.w;
        v[4] = v1.x; v[5] = v1.y; v[6] = v1.z; v[7] = v1.w;
    } else if (n < 136) {
        int i = n - 128, hh = i & 3, lr = i >> 2;
        const float* av = lr ? ar : al;
#pragma unroll
        for (int j = 0; j < 8; j++) v[j] = 0.f;
        for (int c = 0; c < 32; c++) {
            float a = av[hh * 32 + c];
            const float* wp = W + (size_t)(hh * 32 + c) * 256 + kg * 8;
#pragma unroll
            for (int j = 0; j < 8; j++) v[j] += a * wp[j];
        }
    } else {
#pragma unroll
        for (int j = 0; j < 8; j++) v[j] = 0.f;
    }
    short s8[8];
#pragma unroll
    for (int j = 0; j < 8; j++) s8[j] = (short)f2bf(v[j]);
    int kstep = kg >> 2, ntile = n >> 4;
    int L     = (kg & 3) * 16 + (n & 15);
    int slot  = kstep * 9 + ntile;
    *(short8v*)&wfrag[(slot * 64 + L) * 8] = *(short8v*)s8;
}

// ---------------- MFMA GEMM + fused el/er ------------------------------------
// block = 256 thr (4 waves); tile 64 nodes x 128 outs; wave = 16 rows.
// W ntiles 0..7 staged linearly into 64 KB LDS; ntile 8 (attn cols) read from
// global (8 KB, L2-resident). Wave's whole A-slice (16 dwordx4/lane) is issued
// up-front so HBM latency is paid once, not per-ks.
__global__ __launch_bounds__(256) void k_gemm(const float* __restrict__ feat,
                                              const short* __restrict__ wfrag,
                                              unsigned short* __restrict__ hb,
                                              float* __restrict__ el,
                                              float* __restrict__ er, int N) {
    __shared__ short wlds[32768];   // 64 KB: slots ks*8+nt (nt<8)
    const int t    = threadIdx.x;
    const int lane = t & 63;
    const int wave = t >> 6;
    const int n0   = blockIdx.x * 64;
    const int g    = lane >> 4;     // k-quad
    const int c    = lane & 15;

    // ---- stage W ntiles 0..7: linear 16 B chunks, skip every 9th slot
#pragma unroll
    for (int i = 0; i < 16; i++) {
        int p  = t + i * 256;                   // chunk 0..4095
        int sl = p >> 6, li = p & 63;           // lds slot, lane-in-slot
        int gs = (sl >> 3) * 9 + (sl & 7);      // global slot
        *(short8v*)&wlds[(size_t)p * 8] =
            *(const short8v*)&wfrag[((size_t)gs * 64 + li) * 8];
    }

    // ---- issue the wave's entire A slice (before the barrier: independent)
    const int row = n0 + wave * 16 + c;
    const int rc  = row < N ? row : N - 1;
    const float* ap = feat + (size_t)rc * 256 + g * 8;
    float4 a4[16];
#pragma unroll
    for (int ks = 0; ks < 8; ks++) {
        a4[2 * ks]     = *(const float4*)(ap + ks * 32);
        a4[2 * ks + 1] = *(const float4*)(ap + ks * 32 + 4);
    }

    __syncthreads();

    f32x4 acc[9];
#pragma unroll
    for (int nt = 0; nt < 9; nt++) acc[nt] = (f32x4){0.f, 0.f, 0.f, 0.f};

#pragma unroll
    for (int ks = 0; ks < 8; ks++) {
        float4 v0 = a4[2 * ks], v1 = a4[2 * ks + 1];
        short s8[8];
        s8[0] = (short)f2bf(v0.x); s8[1] = (short)f2bf(v0.y);
        s8[2] = (short)f2bf(v0.z); s8[3] = (short)f2bf(v0.w);
        s8[4] = (short)f2bf(v1.x); s8[5] = (short)f2bf(v1.y);
        s8[6] = (short)f2bf(v1.z); s8[7] = (short)f2bf(v1.w);
        short8v afrag = *(short8v*)s8;
        // attn ntile from global (L1/L2-resident 8 KB)
        short8v b8 = *(const short8v*)&wfrag[(((size_t)ks * 9 + 8) * 64 + lane) * 8];
#pragma unroll
        for (int nt = 0; nt < 8; nt++) {
            short8v b = *(short8v*)&wlds[(((size_t)ks * 8 + nt) * 64 + lane) * 8];
            acc[nt] = __builtin_amdgcn_mfma_f32_16x16x32_bf16(afrag, b, acc[nt], 0, 0, 0);
        }
        acc[8] = __builtin_amdgcn_mfma_f32_16x16x32_bf16(afrag, b8, acc[8], 0, 0, 0);
    }

    // ---- epilogue: C/D layout col = nt*16 + c, row = wave*16 + g*4 + r
#pragma unroll
    for (int r = 0; r < 4; r++) {
        int m = n0 + wave * 16 + g * 4 + r;
        if (m < N) {
#pragma unroll
            for (int nt = 0; nt < 8; nt++)
                hb[(size_t)m * 128 + nt * 16 + c] = f2bf(acc[nt][r]);
            // attn tile: cols 0..3 = el heads, 4..7 = er heads
            float av = acc[8][r];
            if (c < 4)      el[(size_t)m * 4 + c]       = av;
            else if (c < 8) er[(size_t)m * 4 + (c - 4)] = av;
        }
    }
}

// ---------------- CSR build: count / assign ----------------------------------
__global__ void k_count(const int* __restrict__ dst, int* __restrict__ deg, int E) {
    int g = blockIdx.x * blockDim.x + threadIdx.x;
    if (g < E) atomicAdd(&deg[dst[g]], 1);
}

__global__ void k_assign(const int* __restrict__ deg, int* __restrict__ start,
                         int* __restrict__ cursor, int* __restrict__ counter, int N) {
    int g = blockIdx.x * blockDim.x + threadIdx.x;
    int lane = threadIdx.x & 63;
    int d = (g < N) ? deg[g] : 0;
    int incl = d;
#pragma unroll
    for (int o = 1; o < 64; o <<= 1) {
        int y = __shfl_up(incl, o);
        if (lane >= o) incl += y;
    }
    int excl  = incl - d;
    int total = __shfl(incl, 63);
    int base  = 0;
    if (lane == 0) base = atomicAdd(counter, total);
    base = __shfl(base, 0);
    if (g < N) { start[g] = base + excl; cursor[g] = base + excl; }
}

// ---------------- scatter + score: CSR payload (src, fp16 exp(leaky)) --------
// No segment-max subtraction: scores are O(few), exp(score) fp16-safe, softmax
// ratio unchanged.
__global__ void k_scatter(const int* __restrict__ src, const int* __restrict__ dst,
                          const float* __restrict__ el, const float* __restrict__ er,
                          int* __restrict__ cursor, int* __restrict__ src_csr,
                          uint2* __restrict__ ex_csr, int E) {
    int g = blockIdx.x * blockDim.x + threadIdx.x;
    if (g >= E) return;
    int s = src[g], d = dst[g];
    int p = atomicAdd(&cursor[d], 1);
    float4 l = *(const float4*)(el + (size_t)s * 4);
    float4 r = *(const float4*)(er + (size_t)d * 4);
    float t0 = l.x + r.x, t1 = l.y + r.y, t2 = l.z + r.z, t3 = l.w + r.w;
    t0 = t0 > 0.f ? t0 : NEG_SLOPE * t0;
    t1 = t1 > 0.f ? t1 : NEG_SLOPE * t1;
    t2 = t2 > 0.f ? t2 : NEG_SLOPE * t2;
    t3 = t3 > 0.f ? t3 : NEG_SLOPE * t3;
    __half2 lo = __floats2half2_rn(__expf(t0), __expf(t1));
    __half2 hi = __floats2half2_rn(__expf(t2), __expf(t3));
    uint2 pack;
    pack.x = *(unsigned int*)&lo;
    pack.y = *(unsigned int*)&hi;
    src_csr[p] = s;
    ex_csr[p]  = pack;
}

// ---------------- gather-side aggregation: one wave per dst node -------------
// out[n] = bias + hb[n]*sum_e hb[src_e] + (sum_e ex_e hb[src_e]) / sum_e ex_e
__global__ __launch_bounds__(256) void k_agg(
        const unsigned int* __restrict__ hbu,
        const uint2* __restrict__ ex_csr, const int* __restrict__ src_csr,
        const int* __restrict__ start, const int* __restrict__ deg,
        const float* __restrict__ bias, float* __restrict__ out, int N) {
    int wid  = blockIdx.x * 4 + (threadIdx.x >> 6);
    int lane = threadIdx.x & 63;
    if (wid >= N) return;
    int beg = __builtin_amdgcn_readfirstlane(start[wid]);
    int dg  = __builtin_amdgcn_readfirstlane(deg[wid]);
    int head = lane >> 4;   // elements (2*lane, 2*lane+1) share one head

    float S1x = 0.f, S1y = 0.f, S2x = 0.f, S2y = 0.f, dd = 0.f;
    int i = 0;
    for (; i + 4 <= dg; i += 4) {
        int b = beg + i;
        int s0 = src_csr[b], s1 = src_csr[b + 1], s2 = src_csr[b + 2], s3 = src_csr[b + 3];
        uint2 e0 = ex_csr[b], e1 = ex_csr[b + 1], e2 = ex_csr[b + 2], e3 = ex_csr[b + 3];
        unsigned int u0 = hbu[(size_t)s0 * 64 + lane];
        unsigned int u1 = hbu[(size_t)s1 * 64 + lane];
        unsigned int u2 = hbu[(size_t)s2 * 64 + lane];
        unsigned int u3 = hbu[(size_t)s3 * 64 + lane];
        float x0 = uas(u0 << 16), y0 = uas(u0 & 0xFFFF0000u);
        float x1 = uas(u1 << 16), y1 = uas(u1 & 0xFFFF0000u);
        float x2 = uas(u2 << 16), y2 = uas(u2 & 0xFFFF0000u);
        float x3 = uas(u3 << 16), y3 = uas(u3 & 0xFFFF0000u);
        float w0 = pick_ex(e0, head), w1 = pick_ex(e1, head);
        float w2 = pick_ex(e2, head), w3 = pick_ex(e3, head);
        S1x += (x0 + x1) + (x2 + x3);
        S1y += (y0 + y1) + (y2 + y3);
        S2x += w0 * x0 + w1 * x1 + w2 * x2 + w3 * x3;
        S2y += w0 * y0 + w1 * y1 + w2 * y2 + w3 * y3;
        dd  += (w0 + w1) + (w2 + w3);
    }
    for (; i < dg; i++) {
        int b = beg + i;
        int s0 = src_csr[b];
        uint2 e0 = ex_csr[b];
        unsigned int u0 = hbu[(size_t)s0 * 64 + lane];
        float x0 = uas(u0 << 16), y0 = uas(u0 & 0xFFFF0000u);
        float w0 = pick_ex(e0, head);
        S1x += x0; S1y += y0;
        S2x += w0 * x0; S2y += w0 * y0;
        dd  += w0;
    }

    unsigned int uh = hbu[(size_t)wid * 64 + lane];
    float hvx = uas(uh << 16), hvy = uas(uh & 0xFFFF0000u);
    float2 bv = ((const float2*)bias)[lane];
    float inv = dd > 0.f ? 1.f / dd : 0.f;
    float ox = bv.x + hvx * S1x + S2x * inv;
    float oy = bv.y + hvy * S1y + S2y * inv;
    float2 o = {ox, oy};
    ((float2*)(out + (size_t)wid * 128))[lane] = o;
}

extern "C" void kernel_launch(void* const* d_in, const int* in_sizes, int n_in,
                              void* d_out, int out_size, void* d_ws, size_t ws_size,
                              hipStream_t stream) {
    const float* feat = (const float*)d_in[0];
    const float* W_fc = (const float*)d_in[1];
    const float* al   = (const float*)d_in[2];
    const float* ar   = (const float*)d_in[3];
    const float* bias = (const float*)d_in[4];
    const int*   src  = (const int*)d_in[5];
    const int*   dst  = (const int*)d_in[6];
    const int N = in_sizes[0] / 256;
    const int E = in_sizes[5];

    char* ws = (char*)d_ws;
    size_t off = 0;
    unsigned int* hbu = (unsigned int*)(ws + off); off += (size_t)N * 64 * 4; // 25.6 MB
    float* el         = (float*)(ws + off); off += (size_t)N * 4 * 4;         // 1.6 MB
    float* er         = (float*)(ws + off); off += (size_t)N * 4 * 4;         // 1.6 MB
    int* deg          = (int*)(ws + off);   off += (size_t)N * 4;             // \ one
    int* counter      = (int*)(ws + off);   off += 256;                       // / memset
    int* startA       = (int*)(ws + off);   off += (size_t)N * 4;
    int* cursor       = (int*)(ws + off);   off += (size_t)N * 4;
    int* src_csr      = (int*)(ws + off);   off += (size_t)E * 4;             // 4 MB
    uint2* ex_csr     = (uint2*)(ws + off); off += (size_t)E * 8;             // 8 MB
    short* wfrag      = (short*)(ws + off); off += (size_t)72 * 64 * 8 * 2;   // 72 KB

    float* out = (float*)d_out;

    hipMemsetAsync(deg, 0, (size_t)N * 4 + 256, stream);   // deg + counter
    k_prep<<<18, 256, 0, stream>>>(W_fc, al, ar, wfrag);
    k_gemm<<<(N + 63) / 64, 256, 0, stream>>>(feat, wfrag, (unsigned short*)hbu,
                                              el, er, N);
    k_count<<<(E + 255) / 256, 256, 0, stream>>>(dst, deg, E);
    k_assign<<<(N + 255) / 256, 256, 0, stream>>>(deg, startA, cursor, counter, N);
    k_scatter<<<(E + 255) / 256, 256, 0, stream>>>(src, dst, el, er, cursor,
                                                   src_csr, ex_csr, E);
    k_agg<<<(N + 3) / 4, 256, 0, stream>>>(hbu, ex_csr, src_csr, startA, deg,
                                           bias, out, N);
}

// Round 6
// 364.011 us; speedup vs baseline: 1.0886x; 1.0071x over previous
//
#include <hip/hip_runtime.h>
#include <hip/hip_bf16.h>
#include <hip/hip_fp16.h>
#include <math.h>

#define NEG_SLOPE 0.2f

typedef __attribute__((ext_vector_type(8))) short short8v;
typedef __attribute__((ext_vector_type(4))) float f32x4;

__device__ __forceinline__ float uas(unsigned int u) { return __uint_as_float(u); }

__device__ __forceinline__ unsigned short f2bf(float x) {
    __hip_bfloat16 b = __float2bfloat16(x);
    return *(unsigned short*)&b;
}

// ---------------- W prep: extended bf16 fragment image -----------------------
// Extended B matrix W'[144,256]: rows 0..127 = W; rows 128..135 = head-masked
// attn projections vl[4],vr[4]; rows 136..143 = 0.  Fragment layout (9 ntiles):
//   slot(kstep,ntile) = kstep*9+ntile; lane L=(kg&3)*16+(n&15) holds 8 shorts
//   B'[n][k=kstep*32+(L>>4)*8+j]  -> lane-contiguous 16 B.
__global__ void k_prep(const float* __restrict__ W, const float* __restrict__ al,
                       const float* __restrict__ ar, short* __restrict__ wfrag) {
    int p = blockIdx.x * 256 + threadIdx.x;   // n*32+kg, 0..4607
    if (p >= 144 * 32) return;
    int n = p >> 5, kg = p & 31;
    float v[8];
    if (n < 128) {
        const float* wp = W + (size_t)n * 256 + kg * 8;
        float4 v0 = *(const float4*)wp;
        float4 v1 = *(const float4*)(wp + 4);
        v[0] = v0.x; v[1] = v0.y; v[2] = v0.z; v[3] = v0.w;
        v[4] = v1.x; v[5] = v1.y; v[6] = v1.z; v[7] = v1.w;
    } else if (n < 136) {
        int i = n - 128, hh = i & 3, lr = i >> 2;
        const float* av = lr ? ar : al;
#pragma unroll
        for (int j = 0; j < 8; j++) v[j] = 0.f;
        for (int c = 0; c < 32; c++) {
            float a = av[hh * 32 + c];
            const float* wp = W + (size_t)(hh * 32 + c) * 256 + kg * 8;
#pragma unroll
            for (int j = 0; j < 8; j++) v[j] += a * wp[j];
        }
    } else {
#pragma unroll
        for (int j = 0; j < 8; j++) v[j] = 0.f;
    }
    short s8[8];
#pragma unroll
    for (int j = 0; j < 8; j++) s8[j] = (short)f2bf(v[j]);
    int kstep = kg >> 2, ntile = n >> 4;
    int L     = (kg & 3) * 16 + (n & 15);
    int slot  = kstep * 9 + ntile;
    *(short8v*)&wfrag[(slot * 64 + L) * 8] = *(short8v*)s8;
}

// ---------------- MFMA GEMM + fused el/er ------------------------------------
// block = 256 thr (4 waves); tile 64 nodes x 128 outs; wave = 16 rows.
// W ntiles 0..7 staged linearly into 64 KB LDS; ntile 8 (attn cols) read from
// global (8 KB, L2-resident). Wave's whole A-slice (16 dwordx4/lane) issued
// up-front so HBM latency is paid once, not per-ks.
__global__ __launch_bounds__(256) void k_gemm(const float* __restrict__ feat,
                                              const short* __restrict__ wfrag,
                                              unsigned short* __restrict__ hb,
                                              float* __restrict__ el,
                                              float* __restrict__ er, int N) {
    __shared__ short wlds[32768];   // 64 KB: slots ks*8+nt (nt<8)
    const int t    = threadIdx.x;
    const int lane = t & 63;
    const int wave = t >> 6;
    const int n0   = blockIdx.x * 64;
    const int g    = lane >> 4;     // k-quad
    const int c    = lane & 15;

    // ---- stage W ntiles 0..7: linear 16 B chunks, skip every 9th slot
#pragma unroll
    for (int i = 0; i < 16; i++) {
        int p  = t + i * 256;                   // chunk 0..4095
        int sl = p >> 6, li = p & 63;           // lds slot, lane-in-slot
        int gs = (sl >> 3) * 9 + (sl & 7);      // global slot
        *(short8v*)&wlds[(size_t)p * 8] =
            *(const short8v*)&wfrag[((size_t)gs * 64 + li) * 8];
    }

    // ---- issue the wave's entire A slice (before the barrier: independent)
    const int row = n0 + wave * 16 + c;
    const int rc  = row < N ? row : N - 1;
    const float* ap = feat + (size_t)rc * 256 + g * 8;
    float4 a4[16];
#pragma unroll
    for (int ks = 0; ks < 8; ks++) {
        a4[2 * ks]     = *(const float4*)(ap + ks * 32);
        a4[2 * ks + 1] = *(const float4*)(ap + ks * 32 + 4);
    }

    __syncthreads();

    f32x4 acc[9];
#pragma unroll
    for (int nt = 0; nt < 9; nt++) acc[nt] = (f32x4){0.f, 0.f, 0.f, 0.f};

#pragma unroll
    for (int ks = 0; ks < 8; ks++) {
        float4 v0 = a4[2 * ks], v1 = a4[2 * ks + 1];
        short s8[8];
        s8[0] = (short)f2bf(v0.x); s8[1] = (short)f2bf(v0.y);
        s8[2] = (short)f2bf(v0.z); s8[3] = (short)f2bf(v0.w);
        s8[4] = (short)f2bf(v1.x); s8[5] = (short)f2bf(v1.y);
        s8[6] = (short)f2bf(v1.z); s8[7] = (short)f2bf(v1.w);
        short8v afrag = *(short8v*)s8;
        // attn ntile from global (L1/L2-resident 8 KB)
        short8v b8 = *(const short8v*)&wfrag[(((size_t)ks * 9 + 8) * 64 + lane) * 8];
#pragma unroll
        for (int nt = 0; nt < 8; nt++) {
            short8v b = *(short8v*)&wlds[(((size_t)ks * 8 + nt) * 64 + lane) * 8];
            acc[nt] = __builtin_amdgcn_mfma_f32_16x16x32_bf16(afrag, b, acc[nt], 0, 0, 0);
        }
        acc[8] = __builtin_amdgcn_mfma_f32_16x16x32_bf16(afrag, b8, acc[8], 0, 0, 0);
    }

    // ---- epilogue: C/D layout col = nt*16 + c, row = wave*16 + g*4 + r
#pragma unroll
    for (int r = 0; r < 4; r++) {
        int m = n0 + wave * 16 + g * 4 + r;
        if (m < N) {
#pragma unroll
            for (int nt = 0; nt < 8; nt++)
                hb[(size_t)m * 128 + nt * 16 + c] = f2bf(acc[nt][r]);
            // attn tile: cols 0..3 = el heads, 4..7 = er heads
            float av = acc[8][r];
            if (c < 4)      el[(size_t)m * 4 + c]       = av;
            else if (c < 8) er[(size_t)m * 4 + (c - 4)] = av;
        }
    }
}

// ---------------- CSR build: count / assign ----------------------------------
__global__ void k_count(const int* __restrict__ dst, int* __restrict__ deg, int E) {
    int g = blockIdx.x * blockDim.x + threadIdx.x;
    if (g < E) atomicAdd(&deg[dst[g]], 1);
}

__global__ void k_assign(const int* __restrict__ deg, int* __restrict__ start,
                         int* __restrict__ cursor, int* __restrict__ counter, int N) {
    int g = blockIdx.x * blockDim.x + threadIdx.x;
    int lane = threadIdx.x & 63;
    int d = (g < N) ? deg[g] : 0;
    int incl = d;
#pragma unroll
    for (int o = 1; o < 64; o <<= 1) {
        int y = __shfl_up(incl, o);
        if (lane >= o) incl += y;
    }
    int excl  = incl - d;
    int total = __shfl(incl, 63);
    int base  = 0;
    if (lane == 0) base = atomicAdd(counter, total);
    base = __shfl(base, 0);
    if (g < N) { start[g] = base + excl; cursor[g] = base + excl; }
}

// ---------------- scatter: src-only CSR payload (4 B/edge) -------------------
__global__ void k_scatter(const int* __restrict__ src, const int* __restrict__ dst,
                          int* __restrict__ cursor, int* __restrict__ src_csr, int E) {
    int g = blockIdx.x * blockDim.x + threadIdx.x;
    if (g >= E) return;
    int s = src[g], d = dst[g];
    int p = atomicAdd(&cursor[d], 1);
    src_csr[p] = s;
}

// ---------------- gather-side aggregation: one wave per dst node -------------
// w_e = exp(leaky(el[src_e] + er[n])) computed in-kernel (el/er L2-resident;
// er[n] wave-uniform).  out[n] = bias + hb[n]*Σ hb[src] + (Σ w hb[src]) / Σ w
__global__ __launch_bounds__(256) void k_agg(
        const unsigned int* __restrict__ hbu,
        const float* __restrict__ el, const float* __restrict__ er,
        const int* __restrict__ src_csr,
        const int* __restrict__ start, const int* __restrict__ deg,
        const float* __restrict__ bias, float* __restrict__ out, int N) {
    int wid  = blockIdx.x * 4 + (threadIdx.x >> 6);
    int lane = threadIdx.x & 63;
    if (wid >= N) return;
    int beg = __builtin_amdgcn_readfirstlane(start[wid]);
    int dg  = __builtin_amdgcn_readfirstlane(deg[wid]);
    int head = lane >> 4;   // elements (2*lane, 2*lane+1) share one head

    float er_own = er[(size_t)wid * 4 + head];   // wave-uniform per 16-lane group

    float S1x = 0.f, S1y = 0.f, S2x = 0.f, S2y = 0.f, dd = 0.f;
    int i = 0;
    for (; i + 4 <= dg; i += 4) {
        int b = beg + i;
        int s0 = src_csr[b], s1 = src_csr[b + 1], s2 = src_csr[b + 2], s3 = src_csr[b + 3];
        unsigned int u0 = hbu[(size_t)s0 * 64 + lane];
        unsigned int u1 = hbu[(size_t)s1 * 64 + lane];
        unsigned int u2 = hbu[(size_t)s2 * 64 + lane];
        unsigned int u3 = hbu[(size_t)s3 * 64 + lane];
        float t0 = el[(size_t)s0 * 4 + head] + er_own;
        float t1 = el[(size_t)s1 * 4 + head] + er_own;
        float t2 = el[(size_t)s2 * 4 + head] + er_own;
        float t3 = el[(size_t)s3 * 4 + head] + er_own;
        t0 = t0 > 0.f ? t0 : NEG_SLOPE * t0;
        t1 = t1 > 0.f ? t1 : NEG_SLOPE * t1;
        t2 = t2 > 0.f ? t2 : NEG_SLOPE * t2;
        t3 = t3 > 0.f ? t3 : NEG_SLOPE * t3;
        float w0 = __expf(t0), w1 = __expf(t1), w2 = __expf(t2), w3 = __expf(t3);
        float x0 = uas(u0 << 16), y0 = uas(u0 & 0xFFFF0000u);
        float x1 = uas(u1 << 16), y1 = uas(u1 & 0xFFFF0000u);
        float x2 = uas(u2 << 16), y2 = uas(u2 & 0xFFFF0000u);
        float x3 = uas(u3 << 16), y3 = uas(u3 & 0xFFFF0000u);
        S1x += (x0 + x1) + (x2 + x3);
        S1y += (y0 + y1) + (y2 + y3);
        S2x += w0 * x0 + w1 * x1 + w2 * x2 + w3 * x3;
        S2y += w0 * y0 + w1 * y1 + w2 * y2 + w3 * y3;
        dd  += (w0 + w1) + (w2 + w3);
    }
    for (; i < dg; i++) {
        int b = beg + i;
        int s0 = src_csr[b];
        unsigned int u0 = hbu[(size_t)s0 * 64 + lane];
        float t0 = el[(size_t)s0 * 4 + head] + er_own;
        t0 = t0 > 0.f ? t0 : NEG_SLOPE * t0;
        float w0 = __expf(t0);
        float x0 = uas(u0 << 16), y0 = uas(u0 & 0xFFFF0000u);
        S1x += x0; S1y += y0;
        S2x += w0 * x0; S2y += w0 * y0;
        dd  += w0;
    }

    unsigned int uh = hbu[(size_t)wid * 64 + lane];
    float hvx = uas(uh << 16), hvy = uas(uh & 0xFFFF0000u);
    float2 bv = ((const float2*)bias)[lane];
    float inv = dd > 0.f ? 1.f / dd : 0.f;
    float ox = bv.x + hvx * S1x + S2x * inv;
    float oy = bv.y + hvy * S1y + S2y * inv;
    float2 o = {ox, oy};
    ((float2*)(out + (size_t)wid * 128))[lane] = o;
}

extern "C" void kernel_launch(void* const* d_in, const int* in_sizes, int n_in,
                              void* d_out, int out_size, void* d_ws, size_t ws_size,
                              hipStream_t stream) {
    const float* feat = (const float*)d_in[0];
    const float* W_fc = (const float*)d_in[1];
    const float* al   = (const float*)d_in[2];
    const float* ar   = (const float*)d_in[3];
    const float* bias = (const float*)d_in[4];
    const int*   src  = (const int*)d_in[5];
    const int*   dst  = (const int*)d_in[6];
    const int N = in_sizes[0] / 256;
    const int E = in_sizes[5];

    char* ws = (char*)d_ws;
    size_t off = 0;
    unsigned int* hbu = (unsigned int*)(ws + off); off += (size_t)N * 64 * 4; // 25.6 MB
    float* el         = (float*)(ws + off); off += (size_t)N * 4 * 4;         // 1.6 MB
    float* er         = (float*)(ws + off); off += (size_t)N * 4 * 4;         // 1.6 MB
    int* deg          = (int*)(ws + off);   off += (size_t)N * 4;             // \ one
    int* counter      = (int*)(ws + off);   off += 256;                       // / memset
    int* startA       = (int*)(ws + off);   off += (size_t)N * 4;
    int* cursor       = (int*)(ws + off);   off += (size_t)N * 4;
    int* src_csr      = (int*)(ws + off);   off += (size_t)E * 4;             // 4 MB
    short* wfrag      = (short*)(ws + off); off += (size_t)72 * 64 * 8 * 2;   // 72 KB

    float* out = (float*)d_out;

    hipMemsetAsync(deg, 0, (size_t)N * 4 + 256, stream);   // deg + counter
    k_prep<<<18, 256, 0, stream>>>(W_fc, al, ar, wfrag);
    k_gemm<<<(N + 63) / 64, 256, 0, stream>>>(feat, wfrag, (unsigned short*)hbu,
                                              el, er, N);
    k_count<<<(E + 255) / 256, 256, 0, stream>>>(dst, deg, E);
    k_assign<<<(N + 255) / 256, 256, 0, stream>>>(deg, startA, cursor, counter, N);
    k_scatter<<<(E + 255) / 256, 256, 0, stream>>>(src, dst, cursor, src_csr, E);
    k_agg<<<(N + 3) / 4, 256, 0, stream>>>(hbu, el, er, src_csr, startA, deg,
                                           bias, out, N);
}